// Round 10
// baseline (302.903 us; speedup 1.0000x reference)
//
#include <hip/hip_runtime.h>
#include <hip/hip_bf16.h>
#include <math.h>

#define Hdim 1024
#define Bdim 32
#define Ldim 2048
#define Mtot (Bdim*Ldim)   // 65536

typedef __attribute__((ext_vector_type(8))) short short8v;
typedef __attribute__((ext_vector_type(4))) short short4v;
typedef __attribute__((ext_vector_type(4))) float floatx4;

static __device__ inline short f2bf(float f) {
    union { float f; unsigned u; } x; x.f = f;
    unsigned r = x.u + 0x7FFF + ((x.u >> 16) & 1);   // RNE
    return (short)(r >> 16);
}
static __device__ inline float bf2f(short s) {
    union { unsigned u; float f; } x; x.u = ((unsigned)(unsigned short)s) << 16;
    return x.f;
}

static __device__ inline float fast_tanh(float x) {
    float t = 2.0f * x;
    t = fminf(fmaxf(t, -30.0f), 30.0f);
    float e = __expf(t);
    return (e - 1.0f) / (e + 1.0f);
}

typedef __attribute__((address_space(1))) const void GVT;
typedef __attribute__((address_space(3))) void LVT;
static __device__ inline void gload_lds16(const void* g, void* l) {
    __builtin_amdgcn_global_load_lds((GVT*)g, (LVT*)l, 16, 0, 0);
}

// ---------------- Kernel 0a: enc f32 -> bf16 ----------------
__global__ __launch_bounds__(256) void convert_enc_kernel(
    const float* __restrict__ enc, short* __restrict__ enc_bf)
{
    size_t i = ((size_t)blockIdx.x * 256 + threadIdx.x) * 8;
    float4 a = *(const float4*)(enc + i);
    float4 b = *(const float4*)(enc + i + 4);
    short8v o;
    o[0]=f2bf(a.x); o[1]=f2bf(a.y); o[2]=f2bf(a.z); o[3]=f2bf(a.w);
    o[4]=f2bf(b.x); o[5]=f2bf(b.y); o[6]=f2bf(b.z); o[7]=f2bf(b.w);
    *(short8v*)(enc_bf + i) = o;
}

// ---------------- Kernel 0b: W_e f32 -> compact bf16 [1024][1024] ----------------
__global__ __launch_bounds__(256) void convert_w_kernel(
    const float* __restrict__ attn_w, short* __restrict__ w_bf)
{
    int t = blockIdx.x * 256 + threadIdx.x;
    int o = t >> 7;
    int c = t & 127;
    const float* src = attn_w + (size_t)o * 2 * Hdim + Hdim + c * 8;
    float4 a = *(const float4*)(src);
    float4 b = *(const float4*)(src + 4);
    short8v v;
    v[0]=f2bf(a.x); v[1]=f2bf(a.y); v[2]=f2bf(a.z); v[3]=f2bf(a.w);
    v[4]=f2bf(b.x); v[5]=f2bf(b.y); v[6]=f2bf(b.z); v[7]=f2bf(b.w);
    *(short8v*)(w_bf + (size_t)o * Hdim + c * 8) = v;
}

// ---------------- Kernel 1: q[b][o] = hidden[b]·W_h[o] + bias[o] ----------------
__global__ __launch_bounds__(256) void qproj_kernel(
    const float* __restrict__ hidden, const float* __restrict__ attn_w,
    const float* __restrict__ attn_b, float* __restrict__ qbuf)
{
    int w = blockIdx.x * 4 + (threadIdx.x >> 6);
    int lane = threadIdx.x & 63;
    int o = w >> 5;
    int b = w & 31;
    const float* hrow = hidden + b * Hdim;
    const float* wrow = attn_w + (size_t)o * 2 * Hdim;
    float s = 0.f;
    #pragma unroll
    for (int i = 0; i < 16; i++) s += hrow[lane + i*64] * wrow[lane + i*64];
    s += __shfl_xor(s, 1);  s += __shfl_xor(s, 2);  s += __shfl_xor(s, 4);
    s += __shfl_xor(s, 8);  s += __shfl_xor(s, 16); s += __shfl_xor(s, 32);
    if (lane == 0) qbuf[b * Hdim + o] = s + attn_b[o];
}

// ---------------- Kernel 2: m201-style 4-phase/K-tile 256^2 bf16 GEMM + tanh + v-dot ----
// Quadrant = (M-half, N-half): each phase consumes exactly one A-half + one B-half.
// Stage order for t+1: A0@p1, B0@p2, B1@p3, A1@p4 (cover 3-4 phases each).
// vmcnt(4) between MFMA and closing barrier at p1/p2/p4; raw s_barrier (no hidden drains).
// LDS 3-bit XOR swizzle: chunk ^= ((row>>2)<<1)&7 via pre-swizzled global src.
#define NKT 16

__global__ __launch_bounds__(512, 1) void scores_kernel(
    const short* __restrict__ enc_bf,   // [Mtot][1024] bf16
    const short* __restrict__ w_bf,     // [1024][1024] bf16
    const float* __restrict__ qbuf,     // [B][H]
    const float* __restrict__ vvec,     // [H]
    float* __restrict__ spart)          // [4][Mtot]
{
    __shared__ short As[2][2][8192];    // [buf][half][128 rows x 64 cols] = 64 KB
    __shared__ short Bs[2][2][8192];    // 64 KB
    __shared__ float sred[256][4];      //  4 KB

    // XCD swizzle: grid 1024 = 8 XCD x (4 nblk x 32 mtile); nblk fastest
    int hw  = blockIdx.x;
    int xcd = hw & 7;
    int i7  = hw >> 3;
    int nblk  = i7 & 3;
    int mtile = xcd * 32 + (i7 >> 2);
    int m0 = mtile * 256;
    int n0 = nblk * 256;

    int tid = threadIdx.x;
    int w   = tid >> 6;                 // 0..7
    int l   = tid & 63;
    int wr  = w >> 2;                   // 0..1 (M sub within quadrant)
    int wc  = w & 3;                    // 0..3 (N sub within quadrant)
    int r15 = l & 15;
    int kc  = l >> 4;                   // 0..3
    int rg  = l >> 4;

    // staging lane constants: one gload = 8 rows x 128B; lane l -> row l>>3, chunk l&7.
    // swizzle: LDS chunk c holds global chunk c ^ ((row>>2)<<1 & 7); per-load row = w*16 + j*8 + (l>>3)
    // -> swz(j) = (j*4 + ((l>>5)<<1)) & 7
    int lrow = l >> 3;
    int lch  = l & 7;
    int swz0 = ((l >> 5) << 1) & 7;
    int swz1 = (4 + ((l >> 5) << 1)) & 7;
    const int gl0 = lrow * Hdim + ((lch ^ swz0) * 8);
    const int gl1 = lrow * Hdim + ((lch ^ swz1) * 8);

#define STAGE_A(h, bb, k0) do { \
    const short* _g = enc_bf + (size_t)(m0 + (h)*128 + w*16) * Hdim + (k0); \
    gload_lds16(_g + gl0,                      &As[bb][h][w*1024]);       \
    gload_lds16(_g + 8*(size_t)Hdim + gl1,     &As[bb][h][w*1024 + 512]); \
} while (0)
#define STAGE_B(h, bb, k0) do { \
    const short* _g = w_bf + (size_t)(n0 + (h)*128 + w*16) * Hdim + (k0); \
    gload_lds16(_g + gl0,                      &Bs[bb][h][w*1024]);       \
    gload_lds16(_g + 8*(size_t)Hdim + gl1,     &Bs[bb][h][w*1024 + 512]); \
} while (0)

    // read swizzle: chunk c_des of row r lives at c_des ^ (((r>>2)<<1)&7); with our row
    // forms the XOR reduces to (r15>>2)*2 (wr*32, wc*16, mi*8, ni*8 all drop mod 8).
    int q2 = (r15 >> 2) * 2;
#define LDA(h, mi, kk) (*(const short8v*)(&As[cur][h][(wr*64 + (mi)*16 + r15)*64 + ((((kk)*4 + kc) ^ q2) * 8)]))
#define LDB(h, ni, kk) (*(const short8v*)(&Bs[cur][h][(wc*32 + (ni)*16 + r15)*64 + ((((kk)*4 + kc) ^ q2) * 8)]))

    floatx4 accA[4][2], accB[4][2], accC[4][2], accD[4][2];
    #pragma unroll
    for (int i = 0; i < 4; i++)
        #pragma unroll
        for (int j = 0; j < 2; j++) {
            accA[i][j] = (floatx4){0.f,0.f,0.f,0.f};
            accB[i][j] = (floatx4){0.f,0.f,0.f,0.f};
            accC[i][j] = (floatx4){0.f,0.f,0.f,0.f};
            accD[i][j] = (floatx4){0.f,0.f,0.f,0.f};
        }

    short8v af[4][2], bf0[2][2], bf1[2][2];

    // prologue: stage tile0 in order A0,B0,B1,A1; guarantee A0,B0 before p1
    STAGE_A(0, 0, 0); STAGE_B(0, 0, 0); STAGE_B(1, 0, 0); STAGE_A(1, 0, 0);
    asm volatile("s_waitcnt vmcnt(4)" ::: "memory");
    __builtin_amdgcn_s_barrier();

    for (int t = 0; t < NKT; t++) {
        int cur = t & 1;
        int nxt = cur ^ 1;
        int kn  = (t + 1) * 64;
        bool pf = (t < NKT - 1);

        // ---- Phase 1: (qm0,qn0) = A-half0 x B-half0; stage A0(t+1) ----
        #pragma unroll
        for (int mi = 0; mi < 4; mi++)
            #pragma unroll
            for (int kk = 0; kk < 2; kk++) af[mi][kk] = LDA(0, mi, kk);
        #pragma unroll
        for (int ni = 0; ni < 2; ni++)
            #pragma unroll
            for (int kk = 0; kk < 2; kk++) bf0[ni][kk] = LDB(0, ni, kk);
        if (pf) STAGE_A(0, nxt, kn);
        __builtin_amdgcn_s_barrier();
        __builtin_amdgcn_s_setprio(1);
        #pragma unroll
        for (int mi = 0; mi < 4; mi++)
            #pragma unroll
            for (int ni = 0; ni < 2; ni++)
                #pragma unroll
                for (int kk = 0; kk < 2; kk++)
                    accA[mi][ni] = __builtin_amdgcn_mfma_f32_16x16x32_bf16(af[mi][kk], bf0[ni][kk], accA[mi][ni], 0, 0, 0);
        __builtin_amdgcn_s_setprio(0);
        if (pf) asm volatile("s_waitcnt vmcnt(4)" ::: "memory");   // B1(t) landed
        else    asm volatile("s_waitcnt vmcnt(2)" ::: "memory");
        __builtin_amdgcn_s_barrier();

        // ---- Phase 2: (qm0,qn1) = A-half0 x B-half1 (af reused); stage B0(t+1) ----
        #pragma unroll
        for (int ni = 0; ni < 2; ni++)
            #pragma unroll
            for (int kk = 0; kk < 2; kk++) bf1[ni][kk] = LDB(1, ni, kk);
        if (pf) STAGE_B(0, nxt, kn);
        __builtin_amdgcn_s_barrier();
        __builtin_amdgcn_s_setprio(1);
        #pragma unroll
        for (int mi = 0; mi < 4; mi++)
            #pragma unroll
            for (int ni = 0; ni < 2; ni++)
                #pragma unroll
                for (int kk = 0; kk < 2; kk++)
                    accB[mi][ni] = __builtin_amdgcn_mfma_f32_16x16x32_bf16(af[mi][kk], bf1[ni][kk], accB[mi][ni], 0, 0, 0);
        __builtin_amdgcn_s_setprio(0);
        if (pf) asm volatile("s_waitcnt vmcnt(4)" ::: "memory");   // A1(t) landed
        else    asm volatile("s_waitcnt vmcnt(0)" ::: "memory");
        __builtin_amdgcn_s_barrier();

        // ---- Phase 3: (qm1,qn0) = A-half1 x B-half0 (bf0 still live); stage B1(t+1) ----
        #pragma unroll
        for (int mi = 0; mi < 4; mi++)
            #pragma unroll
            for (int kk = 0; kk < 2; kk++) af[mi][kk] = LDA(1, mi, kk);
        if (pf) STAGE_B(1, nxt, kn);
        __builtin_amdgcn_s_barrier();
        __builtin_amdgcn_s_setprio(1);
        #pragma unroll
        for (int mi = 0; mi < 4; mi++)
            #pragma unroll
            for (int ni = 0; ni < 2; ni++)
                #pragma unroll
                for (int kk = 0; kk < 2; kk++)
                    accC[mi][ni] = __builtin_amdgcn_mfma_f32_16x16x32_bf16(af[mi][kk], bf0[ni][kk], accC[mi][ni], 0, 0, 0);
        __builtin_amdgcn_s_setprio(0);
        __builtin_amdgcn_s_barrier();

        // ---- Phase 4: (qm1,qn1) = A-half1 x B-half1 (no reads); stage A1(t+1) ----
        if (pf) STAGE_A(1, nxt, kn);
        __builtin_amdgcn_s_barrier();
        __builtin_amdgcn_s_setprio(1);
        #pragma unroll
        for (int mi = 0; mi < 4; mi++)
            #pragma unroll
            for (int ni = 0; ni < 2; ni++)
                #pragma unroll
                for (int kk = 0; kk < 2; kk++)
                    accD[mi][ni] = __builtin_amdgcn_mfma_f32_16x16x32_bf16(af[mi][kk], bf1[ni][kk], accD[mi][ni], 0, 0, 0);
        __builtin_amdgcn_s_setprio(0);
        if (pf) asm volatile("s_waitcnt vmcnt(4)" ::: "memory");   // A0,B0(t+1) landed
        __builtin_amdgcn_s_barrier();
    }

    // ---- epilogue: tanh(proj + q) * v, reduce over the block's 256 cols ----
    #pragma unroll
    for (int qm = 0; qm < 2; qm++)
        #pragma unroll
        for (int mi = 0; mi < 4; mi++) {
            float rs[4] = {0.f, 0.f, 0.f, 0.f};
            #pragma unroll
            for (int ni = 0; ni < 2; ni++) {
                floatx4 f0 = qm ? accC[mi][ni] : accA[mi][ni];
                floatx4 f1 = qm ? accD[mi][ni] : accB[mi][ni];
                int o0 = n0 + wc*32 + ni*16 + r15;
                int o1 = o0 + 128;
                float v0 = vvec[o0], v1 = vvec[o1];
                #pragma unroll
                for (int reg = 0; reg < 4; reg++) {
                    int r = qm*128 + wr*64 + mi*16 + rg*4 + reg;
                    int b = r & 31;
                    rs[reg] += fast_tanh(f0[reg] + qbuf[b * Hdim + o0]) * v0;
                    rs[reg] += fast_tanh(f1[reg] + qbuf[b * Hdim + o1]) * v1;
                }
            }
            #pragma unroll
            for (int reg = 0; reg < 4; reg++) {
                float s = rs[reg];
                s += __shfl_xor(s, 1); s += __shfl_xor(s, 2);
                s += __shfl_xor(s, 4); s += __shfl_xor(s, 8);
                if (r15 == 0) {
                    int r = qm*128 + wr*64 + mi*16 + rg*4 + reg;
                    sred[r][wc] = s;
                }
            }
        }
    __syncthreads();
    if (tid < 256)
        spart[(size_t)nblk * Mtot + m0 + tid] = sred[tid][0] + sred[tid][1] + sred[tid][2] + sred[tid][3];
#undef STAGE_A
#undef STAGE_B
#undef LDA
#undef LDB
}

// ---------------- Kernel 3: reduce 4 partials + softmax over L (per b) ----------------
__global__ __launch_bounds__(256) void softmax_kernel(
    const float* __restrict__ spart,   // [4][Mtot], m = l*32+b
    float* __restrict__ attn)          // [B][L]
{
    int b = blockIdx.x;
    int t = threadIdx.x;
    __shared__ float rmax[4], rsum[4];
    float sv[8];
    float mx = -1e30f;
    #pragma unroll
    for (int i = 0; i < 8; i++) {
        int l = t + i * 256;
        int m = l * Bdim + b;
        float s = 0.f;
        #pragma unroll
        for (int p = 0; p < 4; p++) s += spart[(size_t)p * Mtot + m];
        sv[i] = s;
        mx = fmaxf(mx, s);
    }
    #pragma unroll
    for (int off = 1; off < 64; off <<= 1) mx = fmaxf(mx, __shfl_xor(mx, off));
    if ((t & 63) == 0) rmax[t >> 6] = mx;
    __syncthreads();
    mx = fmaxf(fmaxf(rmax[0], rmax[1]), fmaxf(rmax[2], rmax[3]));
    float sum = 0.f;
    #pragma unroll
    for (int i = 0; i < 8; i++) { sv[i] = __expf(sv[i] - mx); sum += sv[i]; }
    #pragma unroll
    for (int off = 1; off < 64; off <<= 1) sum += __shfl_xor(sum, off);
    if ((t & 63) == 0) rsum[t >> 6] = sum;
    __syncthreads();
    sum = rsum[0] + rsum[1] + rsum[2] + rsum[3];
    float inv = 1.f / sum;
    #pragma unroll
    for (int i = 0; i < 8; i++)
        attn[(size_t)b * Ldim + t + i * 256] = sv[i] * inv;
}

// ---------------- Kernel 4: context partials over L-chunks (bf16 enc) ----------------
__global__ __launch_bounds__(256) void context_part_kernel(
    const short* __restrict__ enc_bf,
    const float* __restrict__ attn,
    float* __restrict__ cpart)         // [64][B][H]
{
    int b = blockIdx.x & 31;
    int c = blockIdx.x >> 5;
    int t = threadIdx.x;
    float a0 = 0.f, a1 = 0.f, a2 = 0.f, a3 = 0.f;
    int l0 = c * 32;
    for (int i = 0; i < 32; i++) {
        int l = l0 + i;
        float a = attn[(size_t)b * Ldim + l];
        short4v e = *(const short4v*)(enc_bf + (size_t)(l * Bdim + b) * Hdim + t * 4);
        a0 += a * bf2f(e.x); a1 += a * bf2f(e.y);
        a2 += a * bf2f(e.z); a3 += a * bf2f(e.w);
    }
    float4 r; r.x = a0; r.y = a1; r.z = a2; r.w = a3;
    *(float4*)(cpart + ((size_t)c * Bdim + b) * Hdim + t * 4) = r;
}

// ---------------- Kernel 5: reduce context partials ----------------
__global__ __launch_bounds__(256) void context_reduce_kernel(
    const float* __restrict__ cpart, float* __restrict__ out)
{
    int idx = blockIdx.x * 256 + threadIdx.x;
    float s = 0.f;
    for (int c = 0; c < 64; c++) s += cpart[(size_t)c * (Bdim * Hdim) + idx];
    out[idx] = s;
}

extern "C" void kernel_launch(void* const* d_in, const int* in_sizes, int n_in,
                              void* d_out, int out_size, void* d_ws, size_t ws_size,
                              hipStream_t stream)
{
    const float* hidden = (const float*)d_in[0];
    const float* enc    = (const float*)d_in[1];   // (L,B,H), m = l*32+b
    const float* attn_w = (const float*)d_in[2];
    const float* attn_b = (const float*)d_in[3];
    const float* vvec   = (const float*)d_in[4];
    float* out = (float*)d_out;

    char* ws = (char*)d_ws;
    size_t off = 0;
    short* enc_bf = (short*)(ws + off); off += (size_t)Mtot * Hdim * 2;       // 134.2 MB
    short* w_bf   = (short*)(ws + off); off += (size_t)Hdim * Hdim * 2;       //   2.1 MB
    float* qbuf   = (float*)(ws + off); off += (size_t)Bdim * Hdim * 4;       //   0.13 MB
    float* spart  = (float*)(ws + off); off += (size_t)4 * Mtot * 4;          //   1.0 MB
    float* attnp  = (float*)(ws + off); off += (size_t)Mtot * 4;              //   0.26 MB
    float* cpart  = (float*)(ws + off);                                       //   8.4 MB

    convert_enc_kernel<<<32768, 256, 0, stream>>>(enc, enc_bf);
    convert_w_kernel<<<512, 256, 0, stream>>>(attn_w, w_bf);
    qproj_kernel<<<8192, 256, 0, stream>>>(hidden, attn_w, attn_b, qbuf);
    scores_kernel<<<1024, 512, 0, stream>>>(enc_bf, w_bf, qbuf, vvec, spart);
    softmax_kernel<<<Bdim, 256, 0, stream>>>(spart, attnp);
    context_part_kernel<<<2048, 256, 0, stream>>>(enc_bf, attnp, cpart);
    context_reduce_kernel<<<128, 256, 0, stream>>>(cpart, out);
}

// Round 11
// 293.207 us; speedup vs baseline: 1.0331x; 1.0331x over previous
//
#include <hip/hip_runtime.h>
#include <hip/hip_bf16.h>
#include <math.h>

#define Hdim 1024
#define Bdim 32
#define Ldim 2048
#define Mtot (Bdim*Ldim)   // 65536

typedef __attribute__((ext_vector_type(8))) short short8v;
typedef __attribute__((ext_vector_type(4))) short short4v;
typedef __attribute__((ext_vector_type(4))) float floatx4;

static __device__ inline short f2bf(float f) {
    union { float f; unsigned u; } x; x.f = f;
    unsigned r = x.u + 0x7FFF + ((x.u >> 16) & 1);   // RNE
    return (short)(r >> 16);
}
static __device__ inline short f2bf_hw(float f) {   // hardware RNE cvt (v_cvt_pk-fusable)
    __hip_bfloat16 h = __float2bfloat16(f);
    return *reinterpret_cast<short*>(&h);
}

static __device__ inline float fast_tanh(float x) {
    float t = 2.0f * x;
    t = fminf(fmaxf(t, -30.0f), 30.0f);
    float e = __expf(t);
    return (e - 1.0f) / (e + 1.0f);
}

typedef __attribute__((address_space(1))) const void GVT;
typedef __attribute__((address_space(3))) void LVT;
static __device__ inline void gload_lds16(const void* g, void* l) {
    __builtin_amdgcn_global_load_lds((GVT*)g, (LVT*)l, 16, 0, 0);
}

// ---------------- Kernel 0: W_e (= attn_w[:, H:]) f32 -> compact bf16 [1024][1024] ----------------
__global__ __launch_bounds__(256) void convert_w_kernel(
    const float* __restrict__ attn_w, short* __restrict__ w_bf)
{
    int t = blockIdx.x * 256 + threadIdx.x;
    int o = t >> 7;
    int c = t & 127;
    const float* src = attn_w + (size_t)o * 2 * Hdim + Hdim + c * 8;
    float4 a = *(const float4*)(src);
    float4 b = *(const float4*)(src + 4);
    short8v v;
    v[0]=f2bf(a.x); v[1]=f2bf(a.y); v[2]=f2bf(a.z); v[3]=f2bf(a.w);
    v[4]=f2bf(b.x); v[5]=f2bf(b.y); v[6]=f2bf(b.z); v[7]=f2bf(b.w);
    *(short8v*)(w_bf + (size_t)o * Hdim + c * 8) = v;
}

// ---------------- Kernel 1: q[b][o] = hidden[b]·W_h[o] + bias[o] ----------------
__global__ __launch_bounds__(256) void qproj_kernel(
    const float* __restrict__ hidden, const float* __restrict__ attn_w,
    const float* __restrict__ attn_b, float* __restrict__ qbuf)
{
    int w = blockIdx.x * 4 + (threadIdx.x >> 6);
    int lane = threadIdx.x & 63;
    int o = w >> 5;
    int b = w & 31;
    const float* hrow = hidden + b * Hdim;
    const float* wrow = attn_w + (size_t)o * 2 * Hdim;
    float s = 0.f;
    #pragma unroll
    for (int i = 0; i < 16; i++) s += hrow[lane + i*64] * wrow[lane + i*64];
    s += __shfl_xor(s, 1);  s += __shfl_xor(s, 2);  s += __shfl_xor(s, 4);
    s += __shfl_xor(s, 8);  s += __shfl_xor(s, 16); s += __shfl_xor(s, 32);
    if (lane == 0) qbuf[b * Hdim + o] = s + attn_b[o];
}

// ---------------- Kernel 2: r6-structure GEMM, fused f32->bf16 A-staging, zero-conflict swizzle ----
// A: global f32 -> reg -> hw-cvt -> swizzled ds_write (removes convert_enc kernel).
// B: gload_lds with pre-swizzled per-lane source (LDS dest linear).
// Swizzle (64B rows): 16B-chunk c of row r lives at LDS chunk c ^ ((r>>1)&3).
// Reads: bank = (r15&1)*16 + ((kc^((r15>>1)&3))*4) -> every bank exactly 2 lanes per
// 16-lane kc-group -> structural-minimum, conflict-free.
#define BM 128
#define BN 128
#define BK 32
#define NKT 32

__global__ __launch_bounds__(256, 4) void scores_kernel(
    const float* __restrict__ enc,      // [Mtot][1024] f32 (L,B,H) m=l*32+b
    const short* __restrict__ w_bf,     // [1024][1024] bf16
    const float* __restrict__ qbuf,     // [B][H]
    const float* __restrict__ vvec,     // [H]
    float* __restrict__ spart)          // [8][Mtot]
{
    __shared__ short As[2][BM * BK];    // 2 x 8 KB
    __shared__ short Bs[2][BN * BK];    // 2 x 8 KB
    __shared__ float sred[BM][2];

    // XCD swizzle (r6): 8 nblk sharers of one A-panel on one XCD. grid 4096 = 8*8*64.
    int hw = blockIdx.x;
    int xcd = hw & 7;
    int i5  = hw >> 3;                  // 0..511
    int nblk  = i5 & 7;
    int mtile = xcd * 64 + (i5 >> 3);   // 0..511 bijective
    int m0 = mtile * BM;
    int n0 = nblk * BN;

    int tid  = threadIdx.x;
    int w    = tid >> 6;
    int l    = tid & 63;
    int wr = w >> 1, wc = w & 1;
    int r15 = l & 15;
    int kc  = l >> 4;                   // 0..3
    int rg  = l >> 4;

    // ---- A reg-staging lane constants: slot i covers row i*64 + (tid>>2), chunk tid&3 ----
    int arow = tid >> 2;                // 0..63
    int acol = tid & 3;
    int asw  = (tid >> 3) & 3;          // s(row) = (row>>1)&3, constant across slots
    const float* agp = enc + (size_t)(m0 + arow) * Hdim + acol * 8;
    const int awoff0 = arow * BK + ((acol ^ asw) * 8);          // shorts
    const int awoff1 = (arow + 64) * BK + ((acol ^ asw) * 8);

    // ---- B gload staging: wave w covers rows [w*32, w*32+32), 2 issues of 16 rows ----
    // lane l -> row l>>2, LDS chunk l&3; source chunk = (l&3) ^ ((l>>3)&3)
    const short* bgp = w_bf + (size_t)(n0 + w*32 + (l >> 2)) * Hdim
                            + (((l & 3) ^ ((l >> 3) & 3)) * 8);

#define STAGE_B(bb, k0) do { \
    gload_lds16(bgp + (k0),                      &Bs[bb][(w*32)      * BK]); \
    gload_lds16(bgp + (k0) + 16*(size_t)Hdim,    &Bs[bb][(w*32 + 16) * BK]); \
} while (0)

    // ---- swizzled fragment reads ----
    int q = (r15 >> 1) & 3;
    int rc = (kc ^ q) * 8;
#define LDA(mi) (*(const short8v*)(&As[cur][(wr*64 + (mi)*16 + r15) * BK + rc]))
#define LDB(ni) (*(const short8v*)(&Bs[cur][(wc*64 + (ni)*16 + r15) * BK + rc]))

    floatx4 acc[4][4];
    #pragma unroll
    for (int i = 0; i < 4; i++)
        #pragma unroll
        for (int j = 0; j < 4; j++) acc[i][j] = (floatx4){0.f, 0.f, 0.f, 0.f};

    float4 a00, a01, a10, a11;          // staged A regs (2 slots x 8 floats)

#define LOAD_A(k0) do { \
    a00 = *(const float4*)(agp + (k0)); \
    a01 = *(const float4*)(agp + (k0) + 4); \
    a10 = *(const float4*)(agp + (k0) + 64*(size_t)Hdim); \
    a11 = *(const float4*)(agp + (k0) + 64*(size_t)Hdim + 4); \
} while (0)
#define CVT_WRITE_A(bb) do { \
    short8v s0, s1; \
    s0[0]=f2bf_hw(a00.x); s0[1]=f2bf_hw(a00.y); s0[2]=f2bf_hw(a00.z); s0[3]=f2bf_hw(a00.w); \
    s0[4]=f2bf_hw(a01.x); s0[5]=f2bf_hw(a01.y); s0[6]=f2bf_hw(a01.z); s0[7]=f2bf_hw(a01.w); \
    s1[0]=f2bf_hw(a10.x); s1[1]=f2bf_hw(a10.y); s1[2]=f2bf_hw(a10.z); s1[3]=f2bf_hw(a10.w); \
    s1[4]=f2bf_hw(a11.x); s1[5]=f2bf_hw(a11.y); s1[6]=f2bf_hw(a11.z); s1[7]=f2bf_hw(a11.w); \
    *(short8v*)(&As[bb][awoff0]) = s0; \
    *(short8v*)(&As[bb][awoff1]) = s1; \
} while (0)

    // prologue: tile 0
    LOAD_A(0);
    STAGE_B(0, 0);
    CVT_WRITE_A(0);
    __syncthreads();

    #pragma unroll 2
    for (int kt = 0; kt < NKT; kt++) {
        int cur = kt & 1;
        int nxt = cur ^ 1;
        if (kt < NKT - 1) {
            LOAD_A((kt + 1) * BK);      // global f32 loads (latency covered by MFMA below)
            STAGE_B(nxt, (kt + 1) * BK);
        }
        short8v af[4], bf[4];
        #pragma unroll
        for (int mi = 0; mi < 4; mi++) af[mi] = LDA(mi);
        #pragma unroll
        for (int ni = 0; ni < 4; ni++) bf[ni] = LDB(ni);
        #pragma unroll
        for (int mi = 0; mi < 4; mi++)
            #pragma unroll
            for (int ni = 0; ni < 4; ni++)
                acc[mi][ni] = __builtin_amdgcn_mfma_f32_16x16x32_bf16(af[mi], bf[ni], acc[mi][ni], 0, 0, 0);
        if (kt < NKT - 1) CVT_WRITE_A(nxt);   // waits its own vmcnt; buffer safe (readers done at kt-1)
        __syncthreads();
    }

    // ---- epilogue: tanh(proj + q) * v, reduce over this block's 128 cols ----
    #pragma unroll
    for (int mi = 0; mi < 4; mi++) {
        float rs[4] = {0.f, 0.f, 0.f, 0.f};
        #pragma unroll
        for (int ni = 0; ni < 4; ni++) {
            int o = n0 + wc*64 + ni*16 + r15;
            float vo = vvec[o];
            #pragma unroll
            for (int reg = 0; reg < 4; reg++) {
                int trow = wr*64 + mi*16 + rg*4 + reg;
                int b = trow & 31;
                float p = acc[mi][ni][reg] + qbuf[b * Hdim + o];
                rs[reg] += fast_tanh(p) * vo;
            }
        }
        #pragma unroll
        for (int reg = 0; reg < 4; reg++) {
            float s = rs[reg];
            s += __shfl_xor(s, 1); s += __shfl_xor(s, 2);
            s += __shfl_xor(s, 4); s += __shfl_xor(s, 8);
            if (r15 == 0) {
                int trow = wr*64 + mi*16 + rg*4 + reg;
                sred[trow][wc] = s;
            }
        }
    }
    __syncthreads();
    if (tid < BM)
        spart[(size_t)nblk * Mtot + m0 + tid] = sred[tid][0] + sred[tid][1];
#undef STAGE_B
#undef LDA
#undef LDB
#undef LOAD_A
#undef CVT_WRITE_A
}

// ---------------- Kernel 3: reduce 8 partials + softmax over L (per b) ----------------
__global__ __launch_bounds__(256) void softmax_kernel(
    const float* __restrict__ spart,   // [8][Mtot], m = l*32+b
    float* __restrict__ attn)          // [B][L]
{
    int b = blockIdx.x;
    int t = threadIdx.x;
    __shared__ float rmax[4], rsum[4];
    float sv[8];
    float mx = -1e30f;
    #pragma unroll
    for (int i = 0; i < 8; i++) {
        int l = t + i * 256;
        int m = l * Bdim + b;
        float s = 0.f;
        #pragma unroll
        for (int p = 0; p < 8; p++) s += spart[(size_t)p * Mtot + m];
        sv[i] = s;
        mx = fmaxf(mx, s);
    }
    #pragma unroll
    for (int off = 1; off < 64; off <<= 1) mx = fmaxf(mx, __shfl_xor(mx, off));
    if ((t & 63) == 0) rmax[t >> 6] = mx;
    __syncthreads();
    mx = fmaxf(fmaxf(rmax[0], rmax[1]), fmaxf(rmax[2], rmax[3]));
    float sum = 0.f;
    #pragma unroll
    for (int i = 0; i < 8; i++) { sv[i] = __expf(sv[i] - mx); sum += sv[i]; }
    #pragma unroll
    for (int off = 1; off < 64; off <<= 1) sum += __shfl_xor(sum, off);
    if ((t & 63) == 0) rsum[t >> 6] = sum;
    __syncthreads();
    sum = rsum[0] + rsum[1] + rsum[2] + rsum[3];
    float inv = 1.f / sum;
    #pragma unroll
    for (int i = 0; i < 8; i++)
        attn[(size_t)b * Ldim + t + i * 256] = sv[i] * inv;
}

// ---------------- Kernel 4: context partials over L-chunks (f32 enc) ----------------
__global__ __launch_bounds__(256) void context_part_kernel(
    const float* __restrict__ enc,     // [L*B][H] f32
    const float* __restrict__ attn,    // [B][L]
    float* __restrict__ cpart)         // [64][B][H]
{
    int b = blockIdx.x & 31;
    int c = blockIdx.x >> 5;
    int t = threadIdx.x;
    float4 acc = {0.f, 0.f, 0.f, 0.f};
    int l0 = c * 32;
    for (int i = 0; i < 32; i++) {
        int l = l0 + i;
        float a = attn[(size_t)b * Ldim + l];
        float4 e = *(const float4*)(enc + (size_t)(l * Bdim + b) * Hdim + t * 4);
        acc.x += a * e.x; acc.y += a * e.y; acc.z += a * e.z; acc.w += a * e.w;
    }
    *(float4*)(cpart + ((size_t)c * Bdim + b) * Hdim + t * 4) = acc;
}

// ---------------- Kernel 5: reduce context partials ----------------
__global__ __launch_bounds__(256) void context_reduce_kernel(
    const float* __restrict__ cpart, float* __restrict__ out)
{
    int idx = blockIdx.x * 256 + threadIdx.x;
    float s = 0.f;
    for (int c = 0; c < 64; c++) s += cpart[(size_t)c * (Bdim * Hdim) + idx];
    out[idx] = s;
}

extern "C" void kernel_launch(void* const* d_in, const int* in_sizes, int n_in,
                              void* d_out, int out_size, void* d_ws, size_t ws_size,
                              hipStream_t stream)
{
    const float* hidden = (const float*)d_in[0];
    const float* enc    = (const float*)d_in[1];   // (L,B,H), m = l*32+b
    const float* attn_w = (const float*)d_in[2];
    const float* attn_b = (const float*)d_in[3];
    const float* vvec   = (const float*)d_in[4];
    float* out = (float*)d_out;

    char* ws = (char*)d_ws;
    size_t off = 0;
    short* w_bf   = (short*)(ws + off); off += (size_t)Hdim * Hdim * 2;       // 2.1 MB
    float* qbuf   = (float*)(ws + off); off += (size_t)Bdim * Hdim * 4;       // 0.13 MB
    float* spart  = (float*)(ws + off); off += (size_t)8 * Mtot * 4;          // 2.1 MB
    float* attnp  = (float*)(ws + off); off += (size_t)Mtot * 4;              // 0.26 MB
    float* cpart  = (float*)(ws + off);                                       // 8.4 MB

    convert_w_kernel<<<512, 256, 0, stream>>>(attn_w, w_bf);
    qproj_kernel<<<8192, 256, 0, stream>>>(hidden, attn_w, attn_b, qbuf);
    scores_kernel<<<4096, 256, 0, stream>>>(enc, w_bf, qbuf, vvec, spart);
    softmax_kernel<<<Bdim, 256, 0, stream>>>(spart, attnp);
    context_part_kernel<<<2048, 256, 0, stream>>>(enc, attnp, cpart);
    context_reduce_kernel<<<128, 256, 0, stream>>>(cpart, out);
}